// Round 3
// baseline (296.549 us; speedup 1.0000x reference)
//
#include <hip/hip_runtime.h>
#include <hip/hip_bf16.h>

// Problem constants
#define B_ 4
#define N_ 4096
#define PD_ 1024
#define D_ 16
#define S_ 64
#define ALL_ 1024     // D*S
#define TWOALL_ 2048
#define M_ 16384      // B*N

typedef __bf16 bf16x8 __attribute__((ext_vector_type(8)));
typedef float floatx4 __attribute__((ext_vector_type(4)));

__device__ __forceinline__ float bf2f(unsigned short u) {
    union { unsigned int i; float f; } v;
    v.i = ((unsigned int)u) << 16;
    return v.f;
}

__device__ __forceinline__ unsigned short f2bf(float f) {
    unsigned int x = __float_as_uint(f);
    unsigned int r = (x + 0x7fffu + ((x >> 16) & 1u)) >> 16;
    return (unsigned short)r;
}

// async global->LDS DMA, 16 B per lane; LDS dest = wave-uniform base + lane*16
__device__ __forceinline__ void load_lds_16(const void* g, void* l) {
    __builtin_amdgcn_global_load_lds(
        (const __attribute__((address_space(1))) void*)g,
        (__attribute__((address_space(3))) void*)l, 16, 0, 0);
}

// ---------------- elementwise fp32 -> bf16 ----------------------------------
__global__ __launch_bounds__(256) void convert_f32_bf16(
    const float* __restrict__ in, unsigned short* __restrict__ out, int n4) {
    int i = blockIdx.x * 256 + threadIdx.x;
    if (i >= n4) return;
    float4 v = *(const float4*)(in + (size_t)i * 4);
    ushort4 o;
    o.x = f2bf(v.x); o.y = f2bf(v.y); o.z = f2bf(v.z); o.w = f2bf(v.w);
    *(ushort4*)(out + (size_t)i * 4) = o;
}

// ---------------- tiled transpose fp32 -> bf16 ------------------------------
__global__ void transpose_f32_bf16(const float* __restrict__ in,
                                   unsigned short* __restrict__ out,
                                   int rows, int cols) {
    __shared__ float tile[32][33];
    int bx = blockIdx.x * 32;
    int by = blockIdx.y * 32;
    int tx = threadIdx.x;
    int ty = threadIdx.y;
    #pragma unroll
    for (int i = 0; i < 32; i += 8)
        tile[ty + i][tx] = in[(size_t)(by + ty + i) * cols + bx + tx];
    __syncthreads();
    #pragma unroll
    for (int i = 0; i < 32; i += 8)
        out[(size_t)(bx + ty + i) * rows + by + tx] = f2bf(tile[tx][ty + i]);
}

// ---------------- MFMA bf16 GEMM: 256x256 8-phase, reload quadrants ---------
// Round-3: minimize live registers (spill fix; WRITE_SIZE was the evidence).
// n-major gray quadrant order: ph1(m0n0) ph2(m1n0) ph3(m1n1) ph4(m0n1).
// Live frags = af[4][2] (32 VGPR) + bq[2][2] (16 VGPR); A0 is RE-READ in ph4
// instead of kept live. ds_reads/phase: 12/8/4/8.
// ds addrs: 2 bases + immediates (cg1 = cg0^32). Staging: 8 bumped pointers.
// Staging (iter t): ph1 A(t+1).h1 [buf^1], ph2 A(t+1).h2 [buf^1],
//                   ph4 B(t+2).h1+h2 [buf].
// Safety: buf^1 A-region last read iter t-1 (drained at its final barrier);
// buf B-region reads (ph1 n0, ph3 n1) all complete at ph3 POST_BAR, before
// any wave issues ph4 stages. End-of-iter vmcnt(4) drains tile t+1 exactly,
// leaving B(t+2)x4 in flight. Never vmcnt(0) in the main loop.
#define BM 256
#define BN 256
#define BK 64

#define LOAD_AF(mh_) do { \
    _Pragma("unroll") \
    for (int i_ = 0; i_ < 4; ++i_) { \
        af[i_][0] = *(const bf16x8*)(rdA + bufoff + (mh_) * 4096 + i_ * 1024 + cg0); \
        af[i_][1] = *(const bf16x8*)(rdA + bufoff + (mh_) * 4096 + i_ * 1024 + cg1); \
    } } while (0)

#define LOAD_B(nh_) do { \
    _Pragma("unroll") \
    for (int j_ = 0; j_ < 2; ++j_) { \
        bq[j_][0] = *(const bf16x8*)(rdB + bufoff + (nh_) * 2048 + j_ * 1024 + cg0); \
        bq[j_][1] = *(const bf16x8*)(rdB + bufoff + (nh_) * 2048 + j_ * 1024 + cg1); \
    } } while (0)

// one C-quadrant: 4m x 2n x 2kk = 16 MFMA
#define MMA_Q(mh_, nh_) do { \
    __builtin_amdgcn_s_setprio(1); \
    _Pragma("unroll") \
    for (int kk = 0; kk < 2; ++kk) \
      _Pragma("unroll") \
      for (int i_ = 0; i_ < 4; ++i_) \
        _Pragma("unroll") \
        for (int j_ = 0; j_ < 2; ++j_) \
          acc[(mh_) * 4 + i_][(nh_) * 2 + j_] = \
              __builtin_amdgcn_mfma_f32_16x16x32_bf16( \
                  af[i_][kk], bq[j_][kk], acc[(mh_) * 4 + i_][(nh_) * 2 + j_], 0, 0, 0); \
    __builtin_amdgcn_s_setprio(0); \
  } while (0)

#define MID_BAR() do { \
    __builtin_amdgcn_sched_barrier(0); \
    __builtin_amdgcn_s_barrier(); \
    asm volatile("s_waitcnt lgkmcnt(0)" ::: "memory"); \
    __builtin_amdgcn_sched_barrier(0); \
  } while (0)

#define POST_BAR() do { \
    __builtin_amdgcn_s_barrier(); \
    __builtin_amdgcn_sched_barrier(0); \
  } while (0)

template <int OUT_BF>
__global__ __launch_bounds__(512, 2) void gemm_bf16(
    const unsigned short* __restrict__ A,   // M x K row-major bf16
    const unsigned short* __restrict__ Bt,  // N x K row-major bf16
    const float* __restrict__ bias,         // N fp32
    void* __restrict__ Cv,                  // M x N row-major
    int M, int N, int K, int gxl, int gypx) {

    __shared__ __align__(16) unsigned short As[2][BM * BK];  // 2 x 32 KB
    __shared__ __align__(16) unsigned short Bs[2][BN * BK];  // 2 x 32 KB

    const int tid  = threadIdx.x;
    const int lane = tid & 63;
    const int wave = tid >> 6;      // 0..7
    const int wm   = wave & 1;      // 2 waves down (128 rows each)
    const int wn   = wave >> 1;     // 4 waves across (64 cols each)

    // XCD swizzle (bijective: grid rows divisible by 8)
    const int flat = blockIdx.x;
    const int xcd  = flat & 7;
    const int slot = flat >> 3;
    const int bx   = slot & ((1 << gxl) - 1);
    const int by   = xcd * gypx + (slot >> gxl);
    const int bm0  = by * BM;
    const int bn0  = bx * BN;

    const int lrow = lane & 15;
    const int g0   = lane >> 4;     // k-group 0..3

    // staging lane map within an 8-row x 64-col chunk (1024 B):
    // lane i -> row i>>3, xor-swizzled col group (i&7)^(i>>3)
    const int srow = lane >> 3;
    const int sg   = (lane & 7) ^ srow;

    const unsigned short* a_base =
        A + (size_t)(bm0 + wave * 16 + srow) * K + sg * 8;
    const unsigned short* b_base =
        Bt + (size_t)(bn0 + wave * 16 + srow) * K + sg * 8;

    // ds-read bases: byte math folds to ds_read_b128 with imm offsets
    const int cg0 = (g0 ^ (lrow & 7)) * 8;
    const int cg1 = cg0 ^ 32;                    // ((g0+4)^(lrow&7))*8
    const unsigned short* rdA = &As[0][(wm * 128 + lrow) * 64];
    const unsigned short* rdB = &Bs[0][(wn * 64  + lrow) * 64];

    // staging pointers: A at column (t+1)*64, B at column (t+2)*64; bump +64/iter
    const unsigned short* pA0  = a_base + 64;
    const unsigned short* pA0b = a_base + 64 + (size_t)8   * K;
    const unsigned short* pA1  = a_base + 64 + (size_t)128 * K;
    const unsigned short* pA1b = a_base + 64 + (size_t)136 * K;
    const unsigned short* pB0  = b_base + 128;
    const unsigned short* pB0b = b_base + 128 + (size_t)8   * K;
    const unsigned short* pB1  = b_base + 128 + (size_t)128 * K;
    const unsigned short* pB1b = b_base + 128 + (size_t)136 * K;

    floatx4 acc[8][4] = {};
    bf16x8 af[4][2];        // current A m-half
    bf16x8 bq[2][2];        // current B n-half

    const int NTk = K >> 6;   // # K-tiles (16 here)

    // ---- prologue: tile0 full + B(1) (iter "-1" ph4 role) ----
    {
        unsigned short* d0 = &As[0][wave * 1024];
        load_lds_16(a_base,                      d0);
        load_lds_16(a_base + (size_t)8   * K,    d0 + 512);
        load_lds_16(a_base + (size_t)128 * K,    d0 + 8192);
        load_lds_16(a_base + (size_t)136 * K,    d0 + 8704);
        unsigned short* d1 = &Bs[0][wave * 1024];
        load_lds_16(b_base,                      d1);
        load_lds_16(b_base + (size_t)8   * K,    d1 + 512);
        load_lds_16(b_base + (size_t)128 * K,    d1 + 8192);
        load_lds_16(b_base + (size_t)136 * K,    d1 + 8704);
        if (NTk > 1) {
            unsigned short* d2 = &Bs[1][wave * 1024];
            load_lds_16(b_base + 64,                    d2);
            load_lds_16(b_base + 64 + (size_t)8   * K,  d2 + 512);
            load_lds_16(b_base + 64 + (size_t)128 * K,  d2 + 8192);
            load_lds_16(b_base + 64 + (size_t)136 * K,  d2 + 8704);
            asm volatile("s_waitcnt vmcnt(4)" ::: "memory");
        } else {
            asm volatile("s_waitcnt vmcnt(0)" ::: "memory");
        }
    }
    POST_BAR();

    for (int t = 0; t < NTk; ++t) {
        const int bufoff = (t & 1) << 14;                 // element offset
        unsigned short* dA = &As[(t & 1) ^ 1][wave * 1024];   // A(t+1) dest
        unsigned short* dB = &Bs[t & 1][wave * 1024];         // B(t+2) dest

        // ===== phase 1 (m0,n0): 12 ds_reads; stage A(t+1).h1 [buf^1] =====
        LOAD_AF(0);
        LOAD_B(0);
        if (t + 1 < NTk) {
            load_lds_16(pA0,  dA);
            load_lds_16(pA0b, dA + 512);
        }
        MID_BAR();
        MMA_Q(0, 0);
        POST_BAR();

        // ===== phase 2 (m1,n0): 8 ds_reads (A1); stage A(t+1).h2 =====
        LOAD_AF(1);
        if (t + 1 < NTk) {
            load_lds_16(pA1,  dA + 8192);
            load_lds_16(pA1b, dA + 8704);
        }
        MID_BAR();
        MMA_Q(1, 0);
        POST_BAR();

        // ===== phase 3 (m1,n1): 4 ds_reads (B1); no stage =====
        LOAD_B(1);
        MID_BAR();
        MMA_Q(1, 1);
        POST_BAR();

        // ===== phase 4 (m0,n1): 8 ds_reads (A0 reload); stage B(t+2) =====
        LOAD_AF(0);
        if (t + 2 < NTk) {
            load_lds_16(pB0,  dB);
            load_lds_16(pB0b, dB + 512);
            load_lds_16(pB1,  dB + 8192);
            load_lds_16(pB1b, dB + 8704);
        }
        MID_BAR();
        MMA_Q(0, 1);
        if (t + 2 < NTk) {
            asm volatile("s_waitcnt vmcnt(4)" ::: "memory");
        } else if (t + 1 < NTk) {
            asm volatile("s_waitcnt vmcnt(0)" ::: "memory");
        }
        POST_BAR();

        pA0 += 64; pA0b += 64; pA1 += 64; pA1b += 64;
        pB0 += 64; pB0b += 64; pB1 += 64; pB1b += 64;
    }

    // C/D layout (m89-verified): col = lane&15, row = (lane>>4)*4 + r
    #pragma unroll
    for (int n = 0; n < 4; ++n) {
        int col = bn0 + wn * 64 + n * 16 + (lane & 15);
        float bv = bias[col];
        #pragma unroll
        for (int m = 0; m < 8; ++m) {
            #pragma unroll
            for (int r = 0; r < 4; ++r) {
                int row = bm0 + wm * 128 + m * 16 + (lane >> 4) * 4 + r;
                float v = acc[m][n][r] + bv;
                if (OUT_BF)
                    ((unsigned short*)Cv)[(size_t)row * N + col] = f2bf(v);
                else
                    ((float*)Cv)[(size_t)row * N + col] = v;
            }
        }
    }
}

// ---------------- middle: softmax + banded accumulation (bf16 P) ------------
__global__ __launch_bounds__(256) void middle_kernel(
    const unsigned short* __restrict__ P,
    unsigned short* __restrict__ A2) {

    int idx = blockIdx.x * 256 + threadIdx.x;
    int s   = idx & 63;
    int r   = idx >> 6;            // b*N + n
    int n   = r & (N_ - 1);
    const int t = n & (D_ - 1);
    const int c = n >> 4;

    const unsigned short* Lp = P + (size_t)r * TWOALL_ + s;
    float w[16];
    float mx = -1e30f;
    #pragma unroll
    for (int j = 0; j < 16; ++j) {
        w[j] = bf2f(Lp[j * S_]);
        mx = fmaxf(mx, w[j]);
    }
    float sum = 0.f;
    #pragma unroll
    for (int j = 0; j < 16; ++j) {
        w[j] = __expf(w[j] - mx);
        sum += w[j];
    }
    float inv = 1.0f / sum;

    float q[16];
    #pragma unroll
    for (int d = 0; d < 16; ++d) q[d] = 0.f;

    #pragma unroll
    for (int i = 0; i < 15; ++i) {
        int np = n + i + 1;
        if (np >= N_) np -= N_;
        int b = r >> 12;
        const unsigned short* Rp = P + (((size_t)(b * N_ + np)) * 2 + 1) * ALL_ + s;
        #pragma unroll
        for (int k = 0; k < 15 - i; ++k) {
            q[i + k + 1] += w[i] * bf2f(Rp[k * S_]);
        }
    }

    unsigned short* out = A2 + (size_t)r * ALL_ + s;
    bool last = (c == (N_ / D_) - 1);
    #pragma unroll
    for (int d = 0; d < 16; ++d) {
        float v = (d == 0) ? 0.f : q[d] * inv;
        if (last && (t + d >= D_)) v = 0.f;
        out[d * S_] = f2bf(v);
    }
}

// ---------------- launch -----------------------------------------------------
extern "C" void kernel_launch(void* const* d_in, const int* in_sizes, int n_in,
                              void* d_out, int out_size, void* d_ws, size_t ws_size,
                              hipStream_t stream) {
    const float* x   = (const float*)d_in[0];
    const float* W_r = (const float*)d_in[1];
    const float* b_r = (const float*)d_in[2];
    const float* W_w = (const float*)d_in[3];
    const float* b_w = (const float*)d_in[4];
    float* out = (float*)d_out;

    // workspace: P bf16 67.1MB | xbf 33.6MB | A2 33.6MB | WrT 4.2MB | WwT 2.1MB
    unsigned short* ws  = (unsigned short*)d_ws;
    unsigned short* P   = ws;
    unsigned short* xbf = P   + (size_t)M_ * TWOALL_;
    unsigned short* A2  = xbf + (size_t)M_ * ALL_;
    unsigned short* WrT = A2  + (size_t)M_ * ALL_;
    unsigned short* WwT = WrT + (size_t)TWOALL_ * PD_;

    convert_f32_bf16<<<dim3((M_ * PD_ / 4 + 255) / 256), 256, 0, stream>>>(
        x, xbf, M_ * PD_ / 4);

    dim3 tb(32, 8);
    transpose_f32_bf16<<<dim3(TWOALL_ / 32, PD_ / 32), tb, 0, stream>>>(W_r, WrT, PD_, TWOALL_);
    transpose_f32_bf16<<<dim3(ALL_ / 32, PD_ / 32), tb, 0, stream>>>(W_w, WwT, PD_, ALL_);

    // GEMM1: P(bf16) = x @ W_r + b_r  (M=16384, N=2048, K=1024)
    // grid 8x64 tiles -> 512 blocks, XCD swizzle gxl=3, 8 row-tiles per XCD
    gemm_bf16<1><<<dim3((TWOALL_ / BN) * (M_ / BM)), 512, 0, stream>>>(
        xbf, WrT, b_r, P, M_, TWOALL_, PD_, 3, (M_ / BM) / 8);

    middle_kernel<<<dim3((B_ * N_ * S_) / 256), 256, 0, stream>>>(P, A2);

    // GEMM2: out(f32) = A2 @ W_w + b_w  (M=16384, N=1024, K=1024)
    // grid 4x64 tiles -> 256 blocks, gxl=2
    gemm_bf16<0><<<dim3((ALL_ / BN) * (M_ / BM)), 512, 0, stream>>>(
        A2, WwT, b_w, out, M_, ALL_, PD_, 2, (M_ / BM) / 8);
}

// Round 4
// 271.093 us; speedup vs baseline: 1.0939x; 1.0939x over previous
//
#include <hip/hip_runtime.h>
#include <hip/hip_bf16.h>

// Problem constants
#define B_ 4
#define N_ 4096
#define PD_ 1024
#define D_ 16
#define S_ 64
#define ALL_ 1024     // D*S
#define TWOALL_ 2048
#define M_ 16384      // B*N

typedef __bf16 bf16x8 __attribute__((ext_vector_type(8)));
typedef float floatx4 __attribute__((ext_vector_type(4)));

__device__ __forceinline__ float bf2f(unsigned short u) {
    union { unsigned int i; float f; } v;
    v.i = ((unsigned int)u) << 16;
    return v.f;
}

__device__ __forceinline__ unsigned short f2bf(float f) {
    unsigned int x = __float_as_uint(f);
    unsigned int r = (x + 0x7fffu + ((x >> 16) & 1u)) >> 16;
    return (unsigned short)r;
}

// async global->LDS DMA, 16 B per lane; LDS dest = wave-uniform base + lane*16
__device__ __forceinline__ void load_lds_16(const void* g, void* l) {
    __builtin_amdgcn_global_load_lds(
        (const __attribute__((address_space(1))) void*)g,
        (__attribute__((address_space(3))) void*)l, 16, 0, 0);
}

// ---------------- elementwise fp32 -> bf16 ----------------------------------
__global__ __launch_bounds__(256) void convert_f32_bf16(
    const float* __restrict__ in, unsigned short* __restrict__ out, int n4) {
    int i = blockIdx.x * 256 + threadIdx.x;
    if (i >= n4) return;
    float4 v = *(const float4*)(in + (size_t)i * 4);
    ushort4 o;
    o.x = f2bf(v.x); o.y = f2bf(v.y); o.z = f2bf(v.z); o.w = f2bf(v.w);
    *(ushort4*)(out + (size_t)i * 4) = o;
}

// ---------------- tiled transpose fp32 -> bf16 ------------------------------
__global__ void transpose_f32_bf16(const float* __restrict__ in,
                                   unsigned short* __restrict__ out,
                                   int rows, int cols) {
    __shared__ float tile[32][33];
    int bx = blockIdx.x * 32;
    int by = blockIdx.y * 32;
    int tx = threadIdx.x;
    int ty = threadIdx.y;
    #pragma unroll
    for (int i = 0; i < 32; i += 8)
        tile[ty + i][tx] = in[(size_t)(by + ty + i) * cols + bx + tx];
    __syncthreads();
    #pragma unroll
    for (int i = 0; i < 32; i += 8)
        out[(size_t)(bx + ty + i) * rows + by + tx] = f2bf(tile[tx][ty + i]);
}

// ---------------- MFMA bf16 GEMM (round-0 verified: 70.6us, WRITE clean) ----
// BM=128 x BN=256 tile, 4 waves (2 in M x 2 in N), wave tile 64x128
// (acc 4x8 = 128 fp32/lane). 12 ds_read_b128 : 32 MFMA per k32.
// global_load_lds width=16 staging, XOR-swizzled LDS layout, XCD swizzle.
#define BM 128
#define BN 256
#define BK 64

template <int OUT_BF>
__global__ __launch_bounds__(256, 2) void gemm_bf16(
    const unsigned short* __restrict__ A,   // M x K row-major bf16
    const unsigned short* __restrict__ Bt,  // N x K row-major bf16
    const float* __restrict__ bias,         // N fp32
    void* __restrict__ Cv,                  // M x N row-major
    int M, int N, int K, int gxl) {         // gxl = log2(grid cols)

    __shared__ __align__(16) unsigned short As[BM * BK];  // 16 KB
    __shared__ __align__(16) unsigned short Bs[BN * BK];  // 32 KB

    const int tid  = threadIdx.x;
    const int lane = tid & 63;
    const int wave = tid >> 6;      // 0..3
    const int wm   = wave & 1;      // 2 waves down (64 rows each)
    const int wn   = wave >> 1;     // 2 waves across (128 cols each)

    // XCD swizzle: one y-row's column blocks co-resident on one XCD
    const int flat = blockIdx.x;
    const int xcd  = flat & 7;
    const int slot = flat >> 3;
    const int bx   = slot & ((1 << gxl) - 1);
    const int by   = xcd * 16 + (slot >> gxl);   // grid-y/8 == 16 here
    const int bm0  = by * BM;
    const int bn0  = bx * BN;

    floatx4 acc[4][8] = {};          // 128 fp32 accumulator regs

    const int lrow = lane & 15;

    // staging lane map within an 8-row x 64-col chunk (1024 B):
    // lane i -> row i>>3, xor-swizzled col group (i&7)^(i>>3)
    const int srow = lane >> 3;
    const int sg   = (lane & 7) ^ srow;

    for (int k0 = 0; k0 < K; k0 += BK) {
        // stage A (16 chunks) + B (32 chunks); 4 + 8 chunks per wave
        #pragma unroll
        for (int c = 0; c < 4; ++c) {
            int chunk = wave * 4 + c;            // 0..15
            int row   = chunk * 8 + srow;
            load_lds_16(A + (size_t)(bm0 + row) * K + k0 + sg * 8, As + chunk * 512);
        }
        #pragma unroll
        for (int c = 0; c < 8; ++c) {
            int chunk = wave * 8 + c;            // 0..31
            int row   = chunk * 8 + srow;
            load_lds_16(Bt + (size_t)(bn0 + row) * K + k0 + sg * 8, Bs + chunk * 512);
        }
        __syncthreads();

        #pragma unroll
        for (int kk = 0; kk < 2; ++kk) {
            const int G = (lane >> 4) + kk * 4;   // k-group 0..7
            bf16x8 af[4], bfr[8];
            #pragma unroll
            for (int mt = 0; mt < 4; ++mt) {
                int r = wm * 64 + mt * 16 + lrow;
                af[mt] = *(const bf16x8*)(As + r * BK + ((G ^ (r & 7)) * 8));
            }
            #pragma unroll
            for (int nt = 0; nt < 8; ++nt) {
                int r = wn * 128 + nt * 16 + lrow;
                bfr[nt] = *(const bf16x8*)(Bs + r * BK + ((G ^ (r & 7)) * 8));
            }
            #pragma unroll
            for (int mt = 0; mt < 4; ++mt)
                #pragma unroll
                for (int nt = 0; nt < 8; ++nt)
                    acc[mt][nt] = __builtin_amdgcn_mfma_f32_16x16x32_bf16(
                        af[mt], bfr[nt], acc[mt][nt], 0, 0, 0);
        }
        __syncthreads();
    }

    // C/D layout (m89-verified): col = lane&15, row = (lane>>4)*4 + r
    #pragma unroll
    for (int nt = 0; nt < 8; ++nt) {
        int col = bn0 + wn * 128 + nt * 16 + (lane & 15);
        float bv = bias[col];
        #pragma unroll
        for (int mt = 0; mt < 4; ++mt) {
            #pragma unroll
            for (int r = 0; r < 4; ++r) {
                int row = bm0 + wm * 64 + mt * 16 + (lane >> 4) * 4 + r;
                float v = acc[mt][nt][r] + bv;
                if (OUT_BF)
                    ((unsigned short*)Cv)[(size_t)row * N + col] = f2bf(v);
                else
                    ((float*)Cv)[(size_t)row * N + col] = v;
            }
        }
    }
}

// ---------------- middle: softmax + banded accumulation, s x4 vectorized ----
// Round-4 change: 4 s-columns per thread, ushort4 (8 B) loads/stores.
// Mechanism (G13): hipcc never vectorizes scalar bf16 access; the old kernel
// issued 136 scalar 2B VMEM loads + 16 scalar 2B stores per thread. The
// s-dimension is contiguous, so ushort4 cuts VMEM + address-VALU instruction
// count 4x per element; coalescing preserved (16 lanes x 8 B = 128 B).
// All arrays statically indexed after unroll (no scratch, rule #20).
__global__ __launch_bounds__(256) void middle_kernel(
    const unsigned short* __restrict__ P,
    unsigned short* __restrict__ A2) {

    int idx = blockIdx.x * 256 + threadIdx.x;
    int s   = (idx & 15) * 4;      // 4 consecutive s-columns
    int r   = idx >> 4;            // b*N + n
    int n   = r & (N_ - 1);
    const int t = n & (D_ - 1);
    const int c = n >> 4;
    const int b = r >> 12;

    const unsigned short* Lp = P + (size_t)r * TWOALL_ + s;

    float4 w[16];
    float4 mx = make_float4(-1e30f, -1e30f, -1e30f, -1e30f);
    #pragma unroll
    for (int j = 0; j < 16; ++j) {
        ushort4 u = *(const ushort4*)(Lp + j * S_);
        w[j] = make_float4(bf2f(u.x), bf2f(u.y), bf2f(u.z), bf2f(u.w));
        mx.x = fmaxf(mx.x, w[j].x); mx.y = fmaxf(mx.y, w[j].y);
        mx.z = fmaxf(mx.z, w[j].z); mx.w = fmaxf(mx.w, w[j].w);
    }
    float4 sum = make_float4(0.f, 0.f, 0.f, 0.f);
    #pragma unroll
    for (int j = 0; j < 16; ++j) {
        w[j].x = __expf(w[j].x - mx.x); w[j].y = __expf(w[j].y - mx.y);
        w[j].z = __expf(w[j].z - mx.z); w[j].w = __expf(w[j].w - mx.w);
        sum.x += w[j].x; sum.y += w[j].y; sum.z += w[j].z; sum.w += w[j].w;
    }
    float4 inv = make_float4(1.f / sum.x, 1.f / sum.y, 1.f / sum.z, 1.f / sum.w);

    float4 q[16];
    #pragma unroll
    for (int d = 0; d < 16; ++d) q[d] = make_float4(0.f, 0.f, 0.f, 0.f);

    #pragma unroll
    for (int i = 0; i < 15; ++i) {
        int np = n + i + 1;
        if (np >= N_) np -= N_;
        const unsigned short* Rp = P + (((size_t)(b * N_ + np)) * 2 + 1) * ALL_ + s;
        #pragma unroll
        for (int k = 0; k < 15 - i; ++k) {
            ushort4 u = *(const ushort4*)(Rp + k * S_);
            q[i + k + 1].x += w[i].x * bf2f(u.x);
            q[i + k + 1].y += w[i].y * bf2f(u.y);
            q[i + k + 1].z += w[i].z * bf2f(u.z);
            q[i + k + 1].w += w[i].w * bf2f(u.w);
        }
    }

    unsigned short* out = A2 + (size_t)r * ALL_ + s;
    bool last = (c == (N_ / D_) - 1);
    #pragma unroll
    for (int d = 0; d < 16; ++d) {
        float4 v;
        if (d == 0) {
            v = make_float4(0.f, 0.f, 0.f, 0.f);
        } else {
            v = make_float4(q[d].x * inv.x, q[d].y * inv.y,
                            q[d].z * inv.z, q[d].w * inv.w);
        }
        if (last && (t + d >= D_)) v = make_float4(0.f, 0.f, 0.f, 0.f);
        ushort4 o;
        o.x = f2bf(v.x); o.y = f2bf(v.y); o.z = f2bf(v.z); o.w = f2bf(v.w);
        *(ushort4*)(out + d * S_) = o;
    }
}

// ---------------- launch -----------------------------------------------------
extern "C" void kernel_launch(void* const* d_in, const int* in_sizes, int n_in,
                              void* d_out, int out_size, void* d_ws, size_t ws_size,
                              hipStream_t stream) {
    const float* x   = (const float*)d_in[0];
    const float* W_r = (const float*)d_in[1];
    const float* b_r = (const float*)d_in[2];
    const float* W_w = (const float*)d_in[3];
    const float* b_w = (const float*)d_in[4];
    float* out = (float*)d_out;

    // workspace: P bf16 67.1MB | xbf 33.6MB | A2 33.6MB | WrT 4.2MB | WwT 2.1MB
    unsigned short* ws  = (unsigned short*)d_ws;
    unsigned short* P   = ws;
    unsigned short* xbf = P   + (size_t)M_ * TWOALL_;
    unsigned short* A2  = xbf + (size_t)M_ * ALL_;
    unsigned short* WrT = A2  + (size_t)M_ * ALL_;
    unsigned short* WwT = WrT + (size_t)TWOALL_ * PD_;

    convert_f32_bf16<<<dim3((M_ * PD_ / 4 + 255) / 256), 256, 0, stream>>>(
        x, xbf, M_ * PD_ / 4);

    dim3 tb(32, 8);
    transpose_f32_bf16<<<dim3(TWOALL_ / 32, PD_ / 32), tb, 0, stream>>>(W_r, WrT, PD_, TWOALL_);
    transpose_f32_bf16<<<dim3(ALL_ / 32, PD_ / 32), tb, 0, stream>>>(W_w, WwT, PD_, ALL_);

    // GEMM1: P(bf16) = x @ W_r + b_r  (M=16384, N=2048, K=1024), grid 8x128
    gemm_bf16<1><<<dim3((TWOALL_ / BN) * (M_ / BM)), 256, 0, stream>>>(
        xbf, WrT, b_r, P, M_, TWOALL_, PD_, 3);

    // middle: 4 s-columns per thread -> B*N*16 threads
    middle_kernel<<<dim3((B_ * N_ * 16) / 256), 256, 0, stream>>>(P, A2);

    // GEMM2: out(f32) = A2 @ W_w + b_w  (M=16384, N=1024, K=1024), grid 4x128
    gemm_bf16<0><<<dim3((ALL_ / BN) * (M_ / BM)), 256, 0, stream>>>(
        A2, WwT, b_w, out, M_, ALL_, PD_, 2);
}

// Round 5
// 268.139 us; speedup vs baseline: 1.1060x; 1.0110x over previous
//
#include <hip/hip_runtime.h>
#include <hip/hip_bf16.h>

// Problem constants
#define B_ 4
#define N_ 4096
#define PD_ 1024
#define D_ 16
#define S_ 64
#define ALL_ 1024     // D*S
#define TWOALL_ 2048
#define M_ 16384      // B*N

typedef __bf16 bf16x8 __attribute__((ext_vector_type(8)));
typedef float floatx4 __attribute__((ext_vector_type(4)));

__device__ __forceinline__ float bf2f(unsigned short u) {
    union { unsigned int i; float f; } v;
    v.i = ((unsigned int)u) << 16;
    return v.f;
}

__device__ __forceinline__ unsigned short f2bf(float f) {
    unsigned int x = __float_as_uint(f);
    unsigned int r = (x + 0x7fffu + ((x >> 16) & 1u)) >> 16;
    return (unsigned short)r;
}

// async global->LDS DMA, 16 B per lane; LDS dest = wave-uniform base + lane*16
__device__ __forceinline__ void load_lds_16(const void* g, void* l) {
    __builtin_amdgcn_global_load_lds(
        (const __attribute__((address_space(1))) void*)g,
        (__attribute__((address_space(3))) void*)l, 16, 0, 0);
}

// ---------------- tiled transpose fp32 -> bf16 ------------------------------
__global__ void transpose_f32_bf16(const float* __restrict__ in,
                                   unsigned short* __restrict__ out,
                                   int rows, int cols) {
    __shared__ float tile[32][33];
    int bx = blockIdx.x * 32;
    int by = blockIdx.y * 32;
    int tx = threadIdx.x;
    int ty = threadIdx.y;
    #pragma unroll
    for (int i = 0; i < 32; i += 8)
        tile[ty + i][tx] = in[(size_t)(by + ty + i) * cols + bx + tx];
    __syncthreads();
    #pragma unroll
    for (int i = 0; i < 32; i += 8)
        out[(size_t)(bx + ty + i) * rows + by + tx] = f2bf(tile[tx][ty + i]);
}

// ---------------- MFMA bf16 GEMM (round-0 verified core) --------------------
// BM=128 x BN=256 tile, 4 waves (2 in M x 2 in N), wave tile 64x128
// (acc 4x8 = 128 fp32/lane). global_load_lds width=16 staging, XOR-swizzled
// LDS, XCD swizzle. 12 ds_read_b128 : 32 MFMA per k32 (bf16-A path).
//
// Round-5 addition: A_FP32 path fuses the fp32->bf16 convert into A-staging.
//  - A-tile staged as fp32 (32 KB; LDS total 64 KB -> still 2 blocks/CU).
//  - fp32 LDS layout: rows of 256 B, 16 groups of 16 B; logical group g
//    stored at phys g ^ (row&7). DMA source pre-swizzled per lane.
//    Per quarter-wave fragment read: 16 lanes -> 8 phys groups x 2 rows
//    = 2 lanes/bank (free, m136) — same structure as the proven bf16 swizzle.
//  - Fragment read: 2x ds_read_b128 (float4 lo/hi) + 8 RNE casts -> bf16x8.
//    Cast (__bf16)f is RNE, identical to f2bf => numerics unchanged.
#define BM 128
#define BN 256
#define BK 64

template <int A_FP32, int OUT_BF>
__global__ __launch_bounds__(256, 2) void gemm_bf16(
    const void* __restrict__ Av,            // M x lda row-major (bf16 or fp32)
    const unsigned short* __restrict__ Bt,  // N x K row-major bf16
    const float* __restrict__ bias,         // N fp32
    void* __restrict__ Cv,                  // M x N row-major
    int M, int N, int K, int gxl, int lda) {

    __shared__ __align__(16) unsigned short As[A_FP32 ? BM * BK * 2 : BM * BK];
    __shared__ __align__(16) unsigned short Bs[BN * BK];  // 32 KB

    const int tid  = threadIdx.x;
    const int lane = tid & 63;
    const int wave = tid >> 6;      // 0..3
    const int wm   = wave & 1;      // 2 waves down (64 rows each)
    const int wn   = wave >> 1;     // 2 waves across (128 cols each)

    // XCD swizzle: one y-row's column blocks co-resident on one XCD
    const int flat = blockIdx.x;
    const int xcd  = flat & 7;
    const int slot = flat >> 3;
    const int bx   = slot & ((1 << gxl) - 1);
    const int by   = xcd * 16 + (slot >> gxl);   // grid-y/8 == 16 here
    const int bm0  = by * BM;
    const int bn0  = bx * BN;

    floatx4 acc[4][8] = {};          // 128 fp32 accumulator regs

    const int lrow = lane & 15;

    // bf16 staging lane map within an 8-row x 64-col chunk (1024 B):
    // lane i -> row i>>3, xor-swizzled col group (i&7)^(i>>3)
    const int srow = lane >> 3;
    const int sg   = (lane & 7) ^ srow;

    // fp32 staging lane map within a 4-row x 64-col chunk (1024 B):
    // lane i -> row i>>4, 16-B group (i&15), source col pre-swizzled
    const int srow4 = lane >> 4;
    const int sgf0  = lane & 15;

    const unsigned short* Abf = (const unsigned short*)Av;
    const float*          Afp = (const float*)Av;
    const float*          Asf = (const float*)As;

    for (int k0 = 0; k0 < K; k0 += BK) {
        if constexpr (A_FP32) {
            // 32 chunks of 1 KB (4 fp32 rows each); 8 per wave
            #pragma unroll
            for (int c = 0; c < 8; ++c) {
                int chunk = wave * 8 + c;            // 0..31
                int grow  = chunk * 4 + srow4;       // tile row
                int pg    = sgf0 ^ (grow & 7);       // pre-swizzled col group
                load_lds_16(Afp + (size_t)(bm0 + grow) * lda + k0 + pg * 4,
                            As + chunk * 512);
            }
        } else {
            #pragma unroll
            for (int c = 0; c < 4; ++c) {
                int chunk = wave * 4 + c;            // 0..15
                int row   = chunk * 8 + srow;
                load_lds_16(Abf + (size_t)(bm0 + row) * lda + k0 + sg * 8,
                            As + chunk * 512);
            }
        }
        #pragma unroll
        for (int c = 0; c < 8; ++c) {
            int chunk = wave * 8 + c;            // 0..31
            int row   = chunk * 8 + srow;
            load_lds_16(Bt + (size_t)(bn0 + row) * K + k0 + sg * 8, Bs + chunk * 512);
        }
        __syncthreads();

        #pragma unroll
        for (int kk = 0; kk < 2; ++kk) {
            const int G = (lane >> 4) + kk * 4;   // k-group 0..7
            bf16x8 af[4], bfr[8];
            #pragma unroll
            for (int mt = 0; mt < 4; ++mt) {
                int r = wm * 64 + mt * 16 + lrow;
                if constexpr (A_FP32) {
                    const float* rowp = Asf + r * 64;
                    float4 lo = *(const float4*)(rowp + (((2 * G)     ^ (r & 7)) * 4));
                    float4 hi = *(const float4*)(rowp + (((2 * G + 1) ^ (r & 7)) * 4));
                    bf16x8 a;
                    a[0] = (__bf16)lo.x; a[1] = (__bf16)lo.y;
                    a[2] = (__bf16)lo.z; a[3] = (__bf16)lo.w;
                    a[4] = (__bf16)hi.x; a[5] = (__bf16)hi.y;
                    a[6] = (__bf16)hi.z; a[7] = (__bf16)hi.w;
                    af[mt] = a;
                } else {
                    af[mt] = *(const bf16x8*)(As + r * BK + ((G ^ (r & 7)) * 8));
                }
            }
            #pragma unroll
            for (int nt = 0; nt < 8; ++nt) {
                int r = wn * 128 + nt * 16 + lrow;
                bfr[nt] = *(const bf16x8*)(Bs + r * BK + ((G ^ (r & 7)) * 8));
            }
            #pragma unroll
            for (int mt = 0; mt < 4; ++mt)
                #pragma unroll
                for (int nt = 0; nt < 8; ++nt)
                    acc[mt][nt] = __builtin_amdgcn_mfma_f32_16x16x32_bf16(
                        af[mt], bfr[nt], acc[mt][nt], 0, 0, 0);
        }
        __syncthreads();
    }

    // C/D layout (m89-verified): col = lane&15, row = (lane>>4)*4 + r
    #pragma unroll
    for (int nt = 0; nt < 8; ++nt) {
        int col = bn0 + wn * 128 + nt * 16 + (lane & 15);
        float bv = bias[col];
        #pragma unroll
        for (int mt = 0; mt < 4; ++mt) {
            #pragma unroll
            for (int r = 0; r < 4; ++r) {
                int row = bm0 + wm * 64 + mt * 16 + (lane >> 4) * 4 + r;
                float v = acc[mt][nt][r] + bv;
                if (OUT_BF)
                    ((unsigned short*)Cv)[(size_t)row * N + col] = f2bf(v);
                else
                    ((float*)Cv)[(size_t)row * N + col] = v;
            }
        }
    }
}

// ---------------- middle: softmax + banded accumulation (scalar, in-place) --
// Writes output INTO P's L-half (row offset r*2048, cols 0..1023).
// Alias-safety: lane s only reads/writes columns == s (mod 64); L-half of
// row r is touched only by row r's own 64 threads; all L reads complete
// before the first store in-thread; R-half (odd ALL_ blocks) is read-only.
__global__ __launch_bounds__(256) void middle_kernel(
    unsigned short* __restrict__ P) {

    int idx = blockIdx.x * 256 + threadIdx.x;
    int s   = idx & 63;
    int r   = idx >> 6;            // b*N + n
    int n   = r & (N_ - 1);
    const int t = n & (D_ - 1);
    const int c = n >> 4;

    const unsigned short* Lp = P + (size_t)r * TWOALL_ + s;
    float w[16];
    float mx = -1e30f;
    #pragma unroll
    for (int j = 0; j < 16; ++j) {
        w[j] = bf2f(Lp[j * S_]);
        mx = fmaxf(mx, w[j]);
    }
    float sum = 0.f;
    #pragma unroll
    for (int j = 0; j < 16; ++j) {
        w[j] = __expf(w[j] - mx);
        sum += w[j];
    }
    float inv = 1.0f / sum;

    float q[16];
    #pragma unroll
    for (int d = 0; d < 16; ++d) q[d] = 0.f;

    #pragma unroll
    for (int i = 0; i < 15; ++i) {
        int np = n + i + 1;
        if (np >= N_) np -= N_;
        int b = r >> 12;
        const unsigned short* Rp = P + (((size_t)(b * N_ + np)) * 2 + 1) * ALL_ + s;
        #pragma unroll
        for (int k = 0; k < 15 - i; ++k) {
            q[i + k + 1] += w[i] * bf2f(Rp[k * S_]);
        }
    }

    unsigned short* out = P + (size_t)r * TWOALL_ + s;   // in-place, L-half
    bool last = (c == (N_ / D_) - 1);
    #pragma unroll
    for (int d = 0; d < 16; ++d) {
        float v = (d == 0) ? 0.f : q[d] * inv;
        if (last && (t + d >= D_)) v = 0.f;
        out[d * S_] = f2bf(v);
    }
}

// ---------------- launch -----------------------------------------------------
extern "C" void kernel_launch(void* const* d_in, const int* in_sizes, int n_in,
                              void* d_out, int out_size, void* d_ws, size_t ws_size,
                              hipStream_t stream) {
    const float* x   = (const float*)d_in[0];
    const float* W_r = (const float*)d_in[1];
    const float* b_r = (const float*)d_in[2];
    const float* W_w = (const float*)d_in[3];
    const float* b_w = (const float*)d_in[4];
    float* out = (float*)d_out;

    // workspace: P bf16 67.1MB | WrT 4.2MB | WwT 2.1MB   (total 73.4 MB)
    unsigned short* ws  = (unsigned short*)d_ws;
    unsigned short* P   = ws;
    unsigned short* WrT = P   + (size_t)M_ * TWOALL_;
    unsigned short* WwT = WrT + (size_t)TWOALL_ * PD_;

    dim3 tb(32, 8);
    transpose_f32_bf16<<<dim3(TWOALL_ / 32, PD_ / 32), tb, 0, stream>>>(W_r, WrT, PD_, TWOALL_);
    transpose_f32_bf16<<<dim3(ALL_ / 32, PD_ / 32), tb, 0, stream>>>(W_w, WwT, PD_, ALL_);

    // GEMM1 (fused convert): P(bf16) = bf16(x) @ W_r + b_r
    // A read directly as fp32 (lda=1024); M=16384, N=2048, K=1024; grid 8x128
    gemm_bf16<1, 1><<<dim3((TWOALL_ / BN) * (M_ / BM)), 256, 0, stream>>>(
        x, WrT, b_r, P, M_, TWOALL_, PD_, 3, PD_);

    // middle: in-place into P's L-half
    middle_kernel<<<dim3((B_ * N_ * S_) / 256), 256, 0, stream>>>(P);

    // GEMM2: out(f32) = Pl @ W_w + b_w ; A = P L-half with lda=2048
    // M=16384, N=1024, K=1024; grid 4x128
    gemm_bf16<0, 0><<<dim3((ALL_ / BN) * (M_ / BM)), 256, 0, stream>>>(
        P, WwT, b_w, out, M_, ALL_, PD_, 2, TWOALL_);
}

// Round 6
// 265.422 us; speedup vs baseline: 1.1173x; 1.0102x over previous
//
#include <hip/hip_runtime.h>
#include <hip/hip_bf16.h>

// Problem constants
#define B_ 4
#define N_ 4096
#define PD_ 1024
#define D_ 16
#define S_ 64
#define ALL_ 1024     // D*S
#define TWOALL_ 2048
#define M_ 16384      // B*N

typedef __bf16 bf16x8 __attribute__((ext_vector_type(8)));
typedef float floatx4 __attribute__((ext_vector_type(4)));

__device__ __forceinline__ float bf2f(unsigned short u) {
    union { unsigned int i; float f; } v;
    v.i = ((unsigned int)u) << 16;
    return v.f;
}

__device__ __forceinline__ unsigned short f2bf(float f) {
    unsigned int x = __float_as_uint(f);
    unsigned int r = (x + 0x7fffu + ((x >> 16) & 1u)) >> 16;
    return (unsigned short)r;
}

// async global->LDS DMA, 16 B per lane; LDS dest = wave-uniform base + lane*16
__device__ __forceinline__ void load_lds_16(const void* g, void* l) {
    __builtin_amdgcn_global_load_lds(
        (const __attribute__((address_space(1))) void*)g,
        (__attribute__((address_space(3))) void*)l, 16, 0, 0);
}

// ---------------- tiled transpose fp32 -> bf16 ------------------------------
__global__ void transpose_f32_bf16(const float* __restrict__ in,
                                   unsigned short* __restrict__ out,
                                   int rows, int cols) {
    __shared__ float tile[32][33];
    int bx = blockIdx.x * 32;
    int by = blockIdx.y * 32;
    int tx = threadIdx.x;
    int ty = threadIdx.y;
    #pragma unroll
    for (int i = 0; i < 32; i += 8)
        tile[ty + i][tx] = in[(size_t)(by + ty + i) * cols + bx + tx];
    __syncthreads();
    #pragma unroll
    for (int i = 0; i < 32; i += 8)
        out[(size_t)(bx + ty + i) * rows + by + tx] = f2bf(tile[tx][ty + i]);
}

// ---------------- MFMA bf16 GEMM (round-0 verified core) --------------------
// BM=128 x BN=256 tile, 4 waves (2 in M x 2 in N), wave tile 64x128
// (acc 4x8 = 128 fp32/lane). global_load_lds width=16 staging, XOR-swizzled
// LDS, XCD swizzle. LDS is ALWAYS the round-0 bf16 layout (empirically
// 0-conflict on both staging-write and fragment-read).
//
// Round-6 A_CVT path (fused fp32->bf16 convert, reg-staged):
//  - R5's fp32-in-LDS read was 4.2M-bank-conflicted; instead, keep LDS bf16.
//  - Each lane loads its slot's 8 fp32 (2x float4 from x), converts RNE
//    in-register ((__bf16) cast == f2bf), and ds_write_b128's to the SAME
//    address the round-0 DMA would have written (chunk*1024 + lane*16 B)
//    -> identical bank pattern as the proven DMA staging.
//  - B staging stays async DMA, issued FIRST so A's global loads overlap it.
#define BM 128
#define BN 256
#define BK 64

template <int A_CVT, int OUT_BF>
__global__ __launch_bounds__(256, 2) void gemm_bf16(
    const void* __restrict__ Av,            // M x lda row-major (bf16 or fp32)
    const unsigned short* __restrict__ Bt,  // N x K row-major bf16
    const float* __restrict__ bias,         // N fp32
    void* __restrict__ Cv,                  // M x N row-major
    int M, int N, int K, int gxl, int lda) {

    __shared__ __align__(16) unsigned short As[BM * BK];  // 16 KB
    __shared__ __align__(16) unsigned short Bs[BN * BK];  // 32 KB

    const int tid  = threadIdx.x;
    const int lane = tid & 63;
    const int wave = tid >> 6;      // 0..3
    const int wm   = wave & 1;      // 2 waves down (64 rows each)
    const int wn   = wave >> 1;     // 2 waves across (128 cols each)

    // XCD swizzle: one y-row's column blocks co-resident on one XCD
    const int flat = blockIdx.x;
    const int xcd  = flat & 7;
    const int slot = flat >> 3;
    const int bx   = slot & ((1 << gxl) - 1);
    const int by   = xcd * 16 + (slot >> gxl);   // grid-y/8 == 16 here
    const int bm0  = by * BM;
    const int bn0  = bx * BN;

    floatx4 acc[4][8] = {};          // 128 fp32 accumulator regs

    const int lrow = lane & 15;

    // staging lane map within an 8-row x 64-col chunk (1024 B):
    // lane i -> row i>>3, xor-swizzled col group (i&7)^(i>>3)
    const int srow = lane >> 3;
    const int sg   = (lane & 7) ^ srow;

    const unsigned short* Abf = (const unsigned short*)Av;
    const float*          Afp = (const float*)Av;

    for (int k0 = 0; k0 < K; k0 += BK) {
        // B staging first: async DMA in flight while A's reg-path runs
        #pragma unroll
        for (int c = 0; c < 8; ++c) {
            int chunk = wave * 8 + c;            // 0..31
            int row   = chunk * 8 + srow;
            load_lds_16(Bt + (size_t)(bn0 + row) * K + k0 + sg * 8, Bs + chunk * 512);
        }
        if constexpr (A_CVT) {
            // reg-staged convert: 8 fp32 -> 8 bf16 per chunk-slot per lane
            #pragma unroll
            for (int c = 0; c < 4; ++c) {
                int chunk = wave * 4 + c;        // 0..15
                int row   = chunk * 8 + srow;
                const float* src = Afp + (size_t)(bm0 + row) * lda + k0 + sg * 8;
                float4 lo = *(const float4*)(src);
                float4 hi = *(const float4*)(src + 4);
                bf16x8 v;
                v[0] = (__bf16)lo.x; v[1] = (__bf16)lo.y;
                v[2] = (__bf16)lo.z; v[3] = (__bf16)lo.w;
                v[4] = (__bf16)hi.x; v[5] = (__bf16)hi.y;
                v[6] = (__bf16)hi.z; v[7] = (__bf16)hi.w;
                // same LDS address the DMA would use: chunk*1024B + lane*16B
                *(bf16x8*)(As + chunk * 512 + lane * 8) = v;
            }
        } else {
            #pragma unroll
            for (int c = 0; c < 4; ++c) {
                int chunk = wave * 4 + c;            // 0..15
                int row   = chunk * 8 + srow;
                load_lds_16(Abf + (size_t)(bm0 + row) * lda + k0 + sg * 8,
                            As + chunk * 512);
            }
        }
        __syncthreads();

        #pragma unroll
        for (int kk = 0; kk < 2; ++kk) {
            const int G = (lane >> 4) + kk * 4;   // k-group 0..7
            bf16x8 af[4], bfr[8];
            #pragma unroll
            for (int mt = 0; mt < 4; ++mt) {
                int r = wm * 64 + mt * 16 + lrow;
                af[mt] = *(const bf16x8*)(As + r * BK + ((G ^ (r & 7)) * 8));
            }
            #pragma unroll
            for (int nt = 0; nt < 8; ++nt) {
                int r = wn * 128 + nt * 16 + lrow;
                bfr[nt] = *(const bf16x8*)(Bs + r * BK + ((G ^ (r & 7)) * 8));
            }
            #pragma unroll
            for (int mt = 0; mt < 4; ++mt)
                #pragma unroll
                for (int nt = 0; nt < 8; ++nt)
                    acc[mt][nt] = __builtin_amdgcn_mfma_f32_16x16x32_bf16(
                        af[mt], bfr[nt], acc[mt][nt], 0, 0, 0);
        }
        __syncthreads();
    }

    // C/D layout (m89-verified): col = lane&15, row = (lane>>4)*4 + r
    #pragma unroll
    for (int nt = 0; nt < 8; ++nt) {
        int col = bn0 + wn * 128 + nt * 16 + (lane & 15);
        float bv = bias[col];
        #pragma unroll
        for (int mt = 0; mt < 4; ++mt) {
            #pragma unroll
            for (int r = 0; r < 4; ++r) {
                int row = bm0 + wm * 64 + mt * 16 + (lane >> 4) * 4 + r;
                float v = acc[mt][nt][r] + bv;
                if (OUT_BF)
                    ((unsigned short*)Cv)[(size_t)row * N + col] = f2bf(v);
                else
                    ((float*)Cv)[(size_t)row * N + col] = v;
            }
        }
    }
}

// ---------------- middle: softmax + banded accumulation (scalar, in-place) --
// Writes output INTO P's L-half (row offset r*2048, cols 0..1023).
// Alias-safety: lane s only reads/writes columns == s (mod 64); L-half of
// row r is touched only by row r's own 64 threads; all L reads complete
// before the first store in-thread; R-half (odd ALL_ blocks) is read-only.
__global__ __launch_bounds__(256) void middle_kernel(
    unsigned short* __restrict__ P) {

    int idx = blockIdx.x * 256 + threadIdx.x;
    int s   = idx & 63;
    int r   = idx >> 6;            // b*N + n
    int n   = r & (N_ - 1);
    const int t = n & (D_ - 1);
    const int c = n >> 4;

    const unsigned short* Lp = P + (size_t)r * TWOALL_ + s;
    float w[16];
    float mx = -1e30f;
    #pragma unroll
    for (int j = 0; j < 16; ++j) {
        w[j] = bf2f(Lp[j * S_]);
        mx = fmaxf(mx, w[j]);
    }
    float sum = 0.f;
    #pragma unroll
    for (int j = 0; j < 16; ++j) {
        w[j] = __expf(w[j] - mx);
        sum += w[j];
    }
    float inv = 1.0f / sum;

    float q[16];
    #pragma unroll
    for (int d = 0; d < 16; ++d) q[d] = 0.f;

    #pragma unroll
    for (int i = 0; i < 15; ++i) {
        int np = n + i + 1;
        if (np >= N_) np -= N_;
        int b = r >> 12;
        const unsigned short* Rp = P + (((size_t)(b * N_ + np)) * 2 + 1) * ALL_ + s;
        #pragma unroll
        for (int k = 0; k < 15 - i; ++k) {
            q[i + k + 1] += w[i] * bf2f(Rp[k * S_]);
        }
    }

    unsigned short* out = P + (size_t)r * TWOALL_ + s;   // in-place, L-half
    bool last = (c == (N_ / D_) - 1);
    #pragma unroll
    for (int d = 0; d < 16; ++d) {
        float v = (d == 0) ? 0.f : q[d] * inv;
        if (last && (t + d >= D_)) v = 0.f;
        out[d * S_] = f2bf(v);
    }
}

// ---------------- launch -----------------------------------------------------
extern "C" void kernel_launch(void* const* d_in, const int* in_sizes, int n_in,
                              void* d_out, int out_size, void* d_ws, size_t ws_size,
                              hipStream_t stream) {
    const float* x   = (const float*)d_in[0];
    const float* W_r = (const float*)d_in[1];
    const float* b_r = (const float*)d_in[2];
    const float* W_w = (const float*)d_in[3];
    const float* b_w = (const float*)d_in[4];
    float* out = (float*)d_out;

    // workspace: P bf16 67.1MB | WrT 4.2MB | WwT 2.1MB   (total 73.4 MB)
    unsigned short* ws  = (unsigned short*)d_ws;
    unsigned short* P   = ws;
    unsigned short* WrT = P   + (size_t)M_ * TWOALL_;
    unsigned short* WwT = WrT + (size_t)TWOALL_ * PD_;

    dim3 tb(32, 8);
    transpose_f32_bf16<<<dim3(TWOALL_ / 32, PD_ / 32), tb, 0, stream>>>(W_r, WrT, PD_, TWOALL_);
    transpose_f32_bf16<<<dim3(ALL_ / 32, PD_ / 32), tb, 0, stream>>>(W_w, WwT, PD_, ALL_);

    // GEMM1 (fused convert, reg-staged A): P(bf16) = bf16(x) @ W_r + b_r
    // A read directly as fp32 (lda=1024); M=16384, N=2048, K=1024; grid 8x128
    gemm_bf16<1, 1><<<dim3((TWOALL_ / BN) * (M_ / BM)), 256, 0, stream>>>(
        x, WrT, b_r, P, M_, TWOALL_, PD_, 3, PD_);

    // middle: in-place into P's L-half
    middle_kernel<<<dim3((B_ * N_ * S_) / 256), 256, 0, stream>>>(P);

    // GEMM2: out(f32) = Pl @ W_w + b_w ; A = P L-half with lda=2048
    // M=16384, N=1024, K=1024; grid 4x128
    gemm_bf16<0, 0><<<dim3((ALL_ / BN) * (M_ / BM)), 256, 0, stream>>>(
        P, WwT, b_w, out, M_, ALL_, PD_, 2, TWOALL_);
}

// Round 7
// 264.467 us; speedup vs baseline: 1.1213x; 1.0036x over previous
//
#include <hip/hip_runtime.h>
#include <hip/hip_bf16.h>

// Problem constants
#define B_ 4
#define N_ 4096
#define PD_ 1024
#define D_ 16
#define S_ 64
#define ALL_ 1024     // D*S
#define TWOALL_ 2048
#define M_ 16384      // B*N

typedef __bf16 bf16x8 __attribute__((ext_vector_type(8)));
typedef float floatx4 __attribute__((ext_vector_type(4)));

__device__ __forceinline__ float bf2f(unsigned short u) {
    union { unsigned int i; float f; } v;
    v.i = ((unsigned int)u) << 16;
    return v.f;
}

__device__ __forceinline__ unsigned short f2bf(float f) {
    unsigned int x = __float_as_uint(f);
    unsigned int r = (x + 0x7fffu + ((x >> 16) & 1u)) >> 16;
    return (unsigned short)r;
}

// async global->LDS DMA, 16 B per lane; LDS dest = wave-uniform base + lane*16
__device__ __forceinline__ void load_lds_16(const void* g, void* l) {
    __builtin_amdgcn_global_load_lds(
        (const __attribute__((address_space(1))) void*)g,
        (__attribute__((address_space(3))) void*)l, 16, 0, 0);
}

// ---------------- tiled transpose fp32 -> bf16 ------------------------------
__global__ void transpose_f32_bf16(const float* __restrict__ in,
                                   unsigned short* __restrict__ out,
                                   int rows, int cols) {
    __shared__ float tile[32][33];
    int bx = blockIdx.x * 32;
    int by = blockIdx.y * 32;
    int tx = threadIdx.x;
    int ty = threadIdx.y;
    #pragma unroll
    for (int i = 0; i < 32; i += 8)
        tile[ty + i][tx] = in[(size_t)(by + ty + i) * cols + bx + tx];
    __syncthreads();
    #pragma unroll
    for (int i = 0; i < 32; i += 8)
        out[(size_t)(bx + ty + i) * rows + by + tx] = f2bf(tile[tx][ty + i]);
}

// ---------------- MFMA bf16 GEMM (round-0 verified core) --------------------
// BM=128 x BN=256 tile, 4 waves (2 in M x 2 in N), wave tile 64x128
// (acc 4x8 = 128 fp32/lane). global_load_lds width=16 staging, XOR-swizzled
// LDS, XCD swizzle. LDS is ALWAYS the round-0 bf16 layout (empirically
// 0-conflict on both staging-write and fragment-read).
//
// Round-7 A_CVT path (fused fp32->bf16 convert, reg-staged, BATCHED):
//  - R6's version emitted 4 dependent {load->cvt->ds_write} chunks, i.e. 4
//    serialized HBM round-trips per k-iter (+3700 cy, matching the measured
//    9040 vs 5300 cy/iter). Fix per Guideline 7: hoist ALL 8 float4 loads
//    into registers first (static indices -> 32 transient VGPRs), then issue
//    B's async DMA, then convert+ds_write_b128 everything. One vmcnt wait,
//    one HBM latency per k-iter.
//  - LDS addresses identical to R6 (= round-0 DMA pattern, 0 conflicts).
//  - (__bf16) cast is RNE == f2bf => numerics unchanged.
#define BM 128
#define BN 256
#define BK 64

template <int A_CVT, int OUT_BF>
__global__ __launch_bounds__(256, 2) void gemm_bf16(
    const void* __restrict__ Av,            // M x lda row-major (bf16 or fp32)
    const unsigned short* __restrict__ Bt,  // N x K row-major bf16
    const float* __restrict__ bias,         // N fp32
    void* __restrict__ Cv,                  // M x N row-major
    int M, int N, int K, int gxl, int lda) {

    __shared__ __align__(16) unsigned short As[BM * BK];  // 16 KB
    __shared__ __align__(16) unsigned short Bs[BN * BK];  // 32 KB

    const int tid  = threadIdx.x;
    const int lane = tid & 63;
    const int wave = tid >> 6;      // 0..3
    const int wm   = wave & 1;      // 2 waves down (64 rows each)
    const int wn   = wave >> 1;     // 2 waves across (128 cols each)

    // XCD swizzle: one y-row's column blocks co-resident on one XCD
    const int flat = blockIdx.x;
    const int xcd  = flat & 7;
    const int slot = flat >> 3;
    const int bx   = slot & ((1 << gxl) - 1);
    const int by   = xcd * 16 + (slot >> gxl);   // grid-y/8 == 16 here
    const int bm0  = by * BM;
    const int bn0  = bx * BN;

    floatx4 acc[4][8] = {};          // 128 fp32 accumulator regs

    const int lrow = lane & 15;

    // staging lane map within an 8-row x 64-col chunk (1024 B):
    // lane i -> row i>>3, xor-swizzled col group (i&7)^(i>>3)
    const int srow = lane >> 3;
    const int sg   = (lane & 7) ^ srow;

    const unsigned short* Abf = (const unsigned short*)Av;
    const float*          Afp = (const float*)Av;

    for (int k0 = 0; k0 < K; k0 += BK) {
        if constexpr (A_CVT) {
            // 1) issue ALL A global loads first (batched; one latency)
            float4 lo[4], hi[4];
            #pragma unroll
            for (int c = 0; c < 4; ++c) {
                int chunk = wave * 4 + c;        // 0..15
                int row   = chunk * 8 + srow;
                const float* src = Afp + (size_t)(bm0 + row) * lda + k0 + sg * 8;
                lo[c] = *(const float4*)(src);
                hi[c] = *(const float4*)(src + 4);
            }
            // 2) B async DMA in flight while A loads return
            #pragma unroll
            for (int c = 0; c < 8; ++c) {
                int chunk = wave * 8 + c;        // 0..31
                int row   = chunk * 8 + srow;
                load_lds_16(Bt + (size_t)(bn0 + row) * K + k0 + sg * 8,
                            Bs + chunk * 512);
            }
            // 3) convert + write (same LDS addresses as the DMA pattern)
            #pragma unroll
            for (int c = 0; c < 4; ++c) {
                bf16x8 v;
                v[0] = (__bf16)lo[c].x; v[1] = (__bf16)lo[c].y;
                v[2] = (__bf16)lo[c].z; v[3] = (__bf16)lo[c].w;
                v[4] = (__bf16)hi[c].x; v[5] = (__bf16)hi[c].y;
                v[6] = (__bf16)hi[c].z; v[7] = (__bf16)hi[c].w;
                *(bf16x8*)(As + (wave * 4 + c) * 512 + lane * 8) = v;
            }
        } else {
            #pragma unroll
            for (int c = 0; c < 8; ++c) {
                int chunk = wave * 8 + c;            // 0..31
                int row   = chunk * 8 + srow;
                load_lds_16(Bt + (size_t)(bn0 + row) * K + k0 + sg * 8,
                            Bs + chunk * 512);
            }
            #pragma unroll
            for (int c = 0; c < 4; ++c) {
                int chunk = wave * 4 + c;            // 0..15
                int row   = chunk * 8 + srow;
                load_lds_16(Abf + (size_t)(bm0 + row) * lda + k0 + sg * 8,
                            As + chunk * 512);
            }
        }
        __syncthreads();

        #pragma unroll
        for (int kk = 0; kk < 2; ++kk) {
            const int G = (lane >> 4) + kk * 4;   // k-group 0..7
            bf16x8 af[4], bfr[8];
            #pragma unroll
            for (int mt = 0; mt < 4; ++mt) {
                int r = wm * 64 + mt * 16 + lrow;
                af[mt] = *(const bf16x8*)(As + r * BK + ((G ^ (r & 7)) * 8));
            }
            #pragma unroll
            for (int nt = 0; nt < 8; ++nt) {
                int r = wn * 128 + nt * 16 + lrow;
                bfr[nt] = *(const bf16x8*)(Bs + r * BK + ((G ^ (r & 7)) * 8));
            }
            #pragma unroll
            for (int mt = 0; mt < 4; ++mt)
                #pragma unroll
                for (int nt = 0; nt < 8; ++nt)
                    acc[mt][nt] = __builtin_amdgcn_mfma_f32_16x16x32_bf16(
                        af[mt], bfr[nt], acc[mt][nt], 0, 0, 0);
        }
        __syncthreads();
    }

    // C/D layout (m89-verified): col = lane&15, row = (lane>>4)*4 + r
    #pragma unroll
    for (int nt = 0; nt < 8; ++nt) {
        int col = bn0 + wn * 128 + nt * 16 + (lane & 15);
        float bv = bias[col];
        #pragma unroll
        for (int mt = 0; mt < 4; ++mt) {
            #pragma unroll
            for (int r = 0; r < 4; ++r) {
                int row = bm0 + wm * 64 + mt * 16 + (lane >> 4) * 4 + r;
                float v = acc[mt][nt][r] + bv;
                if (OUT_BF)
                    ((unsigned short*)Cv)[(size_t)row * N + col] = f2bf(v);
                else
                    ((float*)Cv)[(size_t)row * N + col] = v;
            }
        }
    }
}

// ---------------- middle: softmax + banded accumulation (scalar, in-place) --
// Writes output INTO P's L-half (row offset r*2048, cols 0..1023).
// Alias-safety: lane s only reads/writes columns == s (mod 64); L-half of
// row r is touched only by row r's own 64 threads; all L reads complete
// before the first store in-thread; R-half (odd ALL_ blocks) is read-only.
__global__ __launch_bounds__(256) void middle_kernel(
    unsigned short* __restrict__ P) {

    int idx = blockIdx.x * 256 + threadIdx.x;
    int s   = idx & 63;
    int r   = idx >> 6;            // b*N + n
    int n   = r & (N_ - 1);
    const int t = n & (D_ - 1);
    const int c = n >> 4;

    const unsigned short* Lp = P + (size_t)r * TWOALL_ + s;
    float w[16];
    float mx = -1e30f;
    #pragma unroll
    for (int j = 0; j < 16; ++j) {
        w[j] = bf2f(Lp[j * S_]);
        mx = fmaxf(mx, w[j]);
    }
    float sum = 0.f;
    #pragma unroll
    for (int j = 0; j < 16; ++j) {
        w[j] = __expf(w[j] - mx);
        sum += w[j];
    }
    float inv = 1.0f / sum;

    float q[16];
    #pragma unroll
    for (int d = 0; d < 16; ++d) q[d] = 0.f;

    #pragma unroll
    for (int i = 0; i < 15; ++i) {
        int np = n + i + 1;
        if (np >= N_) np -= N_;
        int b = r >> 12;
        const unsigned short* Rp = P + (((size_t)(b * N_ + np)) * 2 + 1) * ALL_ + s;
        #pragma unroll
        for (int k = 0; k < 15 - i; ++k) {
            q[i + k + 1] += w[i] * bf2f(Rp[k * S_]);
        }
    }

    unsigned short* out = P + (size_t)r * TWOALL_ + s;   // in-place, L-half
    bool last = (c == (N_ / D_) - 1);
    #pragma unroll
    for (int d = 0; d < 16; ++d) {
        float v = (d == 0) ? 0.f : q[d] * inv;
        if (last && (t + d >= D_)) v = 0.f;
        out[d * S_] = f2bf(v);
    }
}

// ---------------- launch -----------------------------------------------------
extern "C" void kernel_launch(void* const* d_in, const int* in_sizes, int n_in,
                              void* d_out, int out_size, void* d_ws, size_t ws_size,
                              hipStream_t stream) {
    const float* x   = (const float*)d_in[0];
    const float* W_r = (const float*)d_in[1];
    const float* b_r = (const float*)d_in[2];
    const float* W_w = (const float*)d_in[3];
    const float* b_w = (const float*)d_in[4];
    float* out = (float*)d_out;

    // workspace: P bf16 67.1MB | WrT 4.2MB | WwT 2.1MB   (total 73.4 MB)
    unsigned short* ws  = (unsigned short*)d_ws;
    unsigned short* P   = ws;
    unsigned short* WrT = P   + (size_t)M_ * TWOALL_;
    unsigned short* WwT = WrT + (size_t)TWOALL_ * PD_;

    dim3 tb(32, 8);
    transpose_f32_bf16<<<dim3(TWOALL_ / 32, PD_ / 32), tb, 0, stream>>>(W_r, WrT, PD_, TWOALL_);
    transpose_f32_bf16<<<dim3(ALL_ / 32, PD_ / 32), tb, 0, stream>>>(W_w, WwT, PD_, ALL_);

    // GEMM1 (fused convert, batched reg-staged A): P(bf16) = bf16(x) @ W_r + b_r
    // A read directly as fp32 (lda=1024); M=16384, N=2048, K=1024; grid 8x128
    gemm_bf16<1, 1><<<dim3((TWOALL_ / BN) * (M_ / BM)), 256, 0, stream>>>(
        x, WrT, b_r, P, M_, TWOALL_, PD_, 3, PD_);

    // middle: in-place into P's L-half
    middle_kernel<<<dim3((B_ * N_ * S_) / 256), 256, 0, stream>>>(P);

    // GEMM2: out(f32) = Pl @ W_w + b_w ; A = P L-half with lda=2048
    // M=16384, N=1024, K=1024; grid 4x128
    gemm_bf16<0, 0><<<dim3((ALL_ / BN) * (M_ / BM)), 256, 0, stream>>>(
        P, WwT, b_w, out, M_, ALL_, PD_, 2, TWOALL_);
}